// Round 6
// baseline (1137.986 us; speedup 1.0000x reference)
//
#include <hip/hip_runtime.h>
#include <hip/hip_bf16.h>
#include <math.h>

#define N_ATOMS 4096
#define N_EDGES 131072

typedef __attribute__((ext_vector_type(4))) float f32x4;

__device__ __forceinline__ float silu_f(float x) { return x / (1.0f + __expf(-x)); }

// ---------------------------------------------------------------------------
// W-prep (f32): gather W_tp (only first 64 out-cols used downstream) into a
// contiguous slab Wsl[s][c][o] (s<9, c<128, o<64), so the TP inner loop can
// stream it with aligned f32x4 loads. row(s,c) per the reference concat.
// ---------------------------------------------------------------------------
__global__ void wprep_kernel(const float* __restrict__ Wtp, float* __restrict__ Wsl)
{
    int idx = blockIdx.x * 256 + threadIdx.x;     // < 9*128*64 = 73728
    int o = idx & 63;
    int c = (idx >> 6) & 127;
    int s = idx >> 13;
    int row = (s == 0) ? c : (s < 4 ? 128 + c * 3 + (s - 1) : 512 + c * 5 + (s - 4));
    Wsl[idx] = Wtp[row * 128 + o];
}

// ---------------------------------------------------------------------------
// Edge kernel (all f32): 64 edges/block, 256 threads.
//  stage1: sh + rbf   stage2: radial1   stage3: radial2 -> RT[c][e] (LDS)
//  TP: C[64e][64o] = sum_s sh_s * (R @ Ws), Ws streamed from global Wsl
//  (16-lane-shared addresses -> L1 broadcast), 4x4 register tiles.
//  Scatter: float atomicAdd into agg[dst][0:64] (+ b_tp).
// ---------------------------------------------------------------------------
__global__ __launch_bounds__(256) void edge_kernel(
    const float* __restrict__ evec, const float* __restrict__ elen,
    const int* __restrict__ eidx,
    const float* __restrict__ Wr1, const float* __restrict__ br1,
    const float* __restrict__ Wr2, const float* __restrict__ br2,
    const float* __restrict__ Wsl, const float* __restrict__ btp,
    float* __restrict__ agg)
{
    __shared__ __align__(16) float shE[64][12];
    __shared__ __align__(16) float rbfT[8][64];
    __shared__ __align__(16) float R1T[64][64];
    __shared__ __align__(16) float RT[128][64];

    const int t  = threadIdx.x;
    const int E0 = blockIdx.x * 64;
    const float PI6 = 0.52359877559829887308f;

    // ---- stage 1: per-edge scalars ----
    if (t < 64) {
        int e = E0 + t;
        float vx = evec[e*3+0], vy = evec[e*3+1], vz = evec[e*3+2];
        float r = sqrtf(vx*vx + vy*vy + vz*vz) + 1e-8f;
        float inv = 1.0f / r;
        float x = vx*inv, y = vy*inv, z = vz*inv;
        shE[t][0] = 1.0f; shE[t][1] = y; shE[t][2] = z; shE[t][3] = x;
        shE[t][4] = 3.0f*z*z - 1.0f; shE[t][5] = x*z; shE[t][6] = y*z;
        shE[t][7] = x*y; shE[t][8] = x*x - y*y;
        shE[t][9] = 0.f; shE[t][10] = 0.f; shE[t][11] = 0.f;
    }
    {
        int e = t & 63, fb = t >> 6;
        float len = elen[E0 + e];
        float env = 0.5f * (cosf(len * PI6) + 1.0f) * (len < 6.0f ? 1.0f : 0.0f);
        float invl = env / len;
        rbfT[fb][e]     = sinf(len * ((float)(fb + 1) * PI6)) * invl;
        rbfT[fb + 4][e] = sinf(len * ((float)(fb + 5) * PI6)) * invl;
    }
    __syncthreads();

    // ---- stage 2: radial1[64] = silu(rbf @ W_r1 + b_r1) ----
    {
        int e = t & 63, g = t >> 6;
        float rb[8];
        #pragma unroll
        for (int f = 0; f < 8; ++f) rb[f] = rbfT[f][e];
        #pragma unroll
        for (int i = 0; i < 16; ++i) {
            int ko = g * 16 + i;
            float acc = br1[ko];
            #pragma unroll
            for (int f = 0; f < 8; ++f) acc = fmaf(rb[f], Wr1[f * 64 + ko], acc);
            R1T[ko][e] = silu_f(acc);
        }
    }
    __syncthreads();

    // ---- stage 3: radial2[128] = silu(radial1 @ W_r2 + b_r2) -> RT[c][e] ----
    {
        const int e0 = (t & 15) * 4;
        const int c0 = (t >> 4) * 8;
        float acc3[4][8];
        #pragma unroll
        for (int i = 0; i < 4; ++i)
            #pragma unroll
            for (int j = 0; j < 8; ++j) acc3[i][j] = br2[c0 + j];
        for (int k = 0; k < 64; ++k) {
            f32x4 a  = *(const f32x4*)&R1T[k][e0];
            f32x4 w0 = *(const f32x4*)&Wr2[k * 128 + c0];
            f32x4 w1 = *(const f32x4*)&Wr2[k * 128 + c0 + 4];
            #pragma unroll
            for (int i = 0; i < 4; ++i) {
                float av = a[i];
                acc3[i][0] = fmaf(av, w0.x, acc3[i][0]);
                acc3[i][1] = fmaf(av, w0.y, acc3[i][1]);
                acc3[i][2] = fmaf(av, w0.z, acc3[i][2]);
                acc3[i][3] = fmaf(av, w0.w, acc3[i][3]);
                acc3[i][4] = fmaf(av, w1.x, acc3[i][4]);
                acc3[i][5] = fmaf(av, w1.y, acc3[i][5]);
                acc3[i][6] = fmaf(av, w1.z, acc3[i][6]);
                acc3[i][7] = fmaf(av, w1.w, acc3[i][7]);
            }
        }
        #pragma unroll
        for (int i = 0; i < 4; ++i)
            #pragma unroll
            for (int j = 0; j < 8; ++j)
                RT[c0 + j][e0 + i] = silu_f(acc3[i][j]);
    }
    __syncthreads();

    // ---- TP phase: acc[4e][4o] = sum_s sh_s * (R @ Ws) ----
    {
        const int e0 = (t & 15) * 4;
        const int o0 = (t >> 4) * 4;
        float acc[4][4] = {};
        for (int s = 0; s < 9; ++s) {
            const float* Wp = Wsl + (s << 13) + o0;   // Wsl[s][k][o0..o0+3]
            float tmp[4][4] = {};
            #pragma unroll 2
            for (int k = 0; k < 128; ++k) {
                f32x4 a4 = *(const f32x4*)&RT[k][e0];
                f32x4 w4 = *(const f32x4*)&Wp[k << 6];
                float av[4] = {a4.x, a4.y, a4.z, a4.w};
                float wv[4] = {w4.x, w4.y, w4.z, w4.w};
                #pragma unroll
                for (int i = 0; i < 4; ++i)
                    #pragma unroll
                    for (int j = 0; j < 4; ++j)
                        tmp[i][j] = fmaf(av[i], wv[j], tmp[i][j]);
            }
            #pragma unroll
            for (int i = 0; i < 4; ++i) {
                float shv = shE[e0 + i][s];
                #pragma unroll
                for (int j = 0; j < 4; ++j)
                    acc[i][j] = fmaf(shv, tmp[i][j], acc[i][j]);
            }
        }
        #pragma unroll
        for (int i = 0; i < 4; ++i) {
            int e = E0 + e0 + i;
            int dst = eidx[N_EDGES + e];
            #pragma unroll
            for (int j = 0; j < 4; ++j)
                atomicAdd(&agg[dst * 64 + o0 + j], acc[i][j] + btp[o0 + j]);
        }
    }
}

// ---------------------------------------------------------------------------
__global__ void combined_kernel(const int* __restrict__ an,
                                const float* __restrict__ emb,
                                const float* __restrict__ agg,
                                float* __restrict__ comb)
{
    int i = blockIdx.x * 256 + threadIdx.x;
    if (i < N_ATOMS * 64) {
        int n = i >> 6, d = i & 63;
        comb[n * 128 + d]      = emb[an[n] * 64 + d];
        comb[n * 128 + 64 + d] = agg[n * 64 + d];
    }
}

// ---------------------------------------------------------------------------
template <int ACT>
__global__ __launch_bounds__(256, 2) void gemm128(
    const float* __restrict__ A, const float* __restrict__ W,
    const float* __restrict__ bias, float* __restrict__ C, int N,
    const float* __restrict__ aux1, const float* __restrict__ aux2)
{
    __shared__ __align__(16) float AT[128][64];
    __shared__ __align__(16) float Ws[128][64];
    const int t  = threadIdx.x;
    const int M0 = blockIdx.x * 64;
    const int N0 = blockIdx.y * 64;

    for (int idx = t; idx < 64 * 128; idx += 256) {
        int m = idx >> 7, k = idx & 127;
        AT[k][m ^ ((k & 15) << 2)] = A[(M0 + m) * 128 + k];
    }
    for (int idx = t; idx < 128 * 64; idx += 256) {
        int k = idx >> 6, o = idx & 63;
        Ws[k][o] = W[k * N + N0 + o];
    }
    __syncthreads();

    const int m0 = (t & 15) * 4;
    const int o0 = (t >> 4) * 4;
    float acc[4][4] = {};
    #pragma unroll 2
    for (int k = 0; k < 128; ++k) {
        int xs = (k & 15) << 2;
        float4 a4 = *(const float4*)&AT[k][m0 ^ xs];
        float4 w4 = *(const float4*)&Ws[k][o0];
        float av[4] = {a4.x, a4.y, a4.z, a4.w};
        float wv[4] = {w4.x, w4.y, w4.z, w4.w};
        #pragma unroll
        for (int i = 0; i < 4; ++i)
            #pragma unroll
            for (int j = 0; j < 4; ++j)
                acc[i][j] = fmaf(av[i], wv[j], acc[i][j]);
    }

    #pragma unroll
    for (int i = 0; i < 4; ++i) {
        int m = M0 + m0 + i;
        #pragma unroll
        for (int j = 0; j < 4; ++j) {
            int o = N0 + o0 + j;
            float v = acc[i][j] + bias[o];
            if (ACT == 1) v = silu_f(v);
            if (ACT == 2) {
                float sg = 1.0f / (1.0f + __expf(-v));
                v = sg * aux1[m * 128 + o] + (1.0f - sg) * aux2[m * 128 + o];
            }
            C[m * N + o] = v;
        }
    }
}

// ---------------------------------------------------------------------------
// f32 flash attention: block = (head, 16-row q-tile) -> 1024 blocks,
// 4 blocks/CU. Online softmax; PT padded to kill bank conflicts.
// qkv layout: [n][384] = [q(128) | k(128) | v(128)].
// ---------------------------------------------------------------------------
__global__ __launch_bounds__(256, 4) void attn_kernel(
    const float* __restrict__ qkv, float* __restrict__ attd)
{
    __shared__ float QT[32][16];
    __shared__ float KT[32][64];
    __shared__ float Vs[64][32];
    __shared__ float PT[64][17];

    const int t = threadIdx.x;
    const int h = blockIdx.x >> 8, qt = blockIdx.x & 255;
    const int N0 = qt * 16;
    const float scale = 0.17677669529663687f; // 1/sqrt(32)

    for (int idx = t; idx < 512; idx += 256) {
        int r = idx & 15, k = idx >> 4;
        QT[k][r] = qkv[(N0 + r) * 384 + h * 32 + k] * scale;
    }

    const int row = t >> 4;         // 16 q-rows
    const int cg  = t & 15;
    const int m0  = cg * 4;         // QK col group
    const int d0  = cg * 2;         // PV dim group

    float run_m = -1e30f, run_l = 0.0f;
    float O0 = 0.f, O1 = 0.f;

    for (int mt = 0; mt < 64; ++mt) {
        __syncthreads();            // prev PV done (and Q staged, iter 0)
        int Mb = mt * 64;
        for (int idx = t; idx < 64 * 32; idx += 256) {
            int mm = idx >> 5, d = idx & 31;
            KT[d][mm] = qkv[(Mb + mm) * 384 + 128 + h * 32 + d];
            Vs[mm][d] = qkv[(Mb + mm) * 384 + 256 + h * 32 + d];
        }
        __syncthreads();

        float s0 = 0.f, s1 = 0.f, s2 = 0.f, s3 = 0.f;
        #pragma unroll 4
        for (int k = 0; k < 32; ++k) {
            float q = QT[k][row];
            float4 kk = *(const float4*)&KT[k][m0];
            s0 = fmaf(q, kk.x, s0);
            s1 = fmaf(q, kk.y, s1);
            s2 = fmaf(q, kk.z, s2);
            s3 = fmaf(q, kk.w, s3);
        }
        float tm = fmaxf(fmaxf(s0, s1), fmaxf(s2, s3));
        tm = fmaxf(tm, __shfl_xor(tm, 1, 16));
        tm = fmaxf(tm, __shfl_xor(tm, 2, 16));
        tm = fmaxf(tm, __shfl_xor(tm, 4, 16));
        tm = fmaxf(tm, __shfl_xor(tm, 8, 16));
        float nm = fmaxf(run_m, tm);
        float c  = __expf(run_m - nm);
        run_m = nm;
        float p0 = __expf(s0 - nm), p1 = __expf(s1 - nm);
        float p2 = __expf(s2 - nm), p3 = __expf(s3 - nm);
        float rs = p0 + p1 + p2 + p3;
        rs += __shfl_xor(rs, 1, 16);
        rs += __shfl_xor(rs, 2, 16);
        rs += __shfl_xor(rs, 4, 16);
        rs += __shfl_xor(rs, 8, 16);
        run_l = run_l * c + rs;
        O0 *= c; O1 *= c;
        PT[m0 + 0][row] = p0;
        PT[m0 + 1][row] = p1;
        PT[m0 + 2][row] = p2;
        PT[m0 + 3][row] = p3;
        __syncthreads();

        #pragma unroll 4
        for (int mm = 0; mm < 64; ++mm) {
            float p = PT[mm][row];
            O0 = fmaf(p, Vs[mm][d0],     O0);
            O1 = fmaf(p, Vs[mm][d0 + 1], O1);
        }
    }

    float invl = 1.0f / run_l;
    attd[(N0 + row) * 128 + h * 32 + d0]     = O0 * invl;
    attd[(N0 + row) * 128 + h * 32 + d0 + 1] = O1 * invl;
}

// ---------------------------------------------------------------------------
extern "C" void kernel_launch(void* const* d_in, const int* in_sizes, int n_in,
                              void* d_out, int out_size, void* d_ws, size_t ws_size,
                              hipStream_t stream) {
    const int*   an    = (const int*)d_in[0];
    const int*   eidx  = (const int*)d_in[2];
    const float* evec  = (const float*)d_in[3];
    const float* elen  = (const float*)d_in[4];
    const float* emb   = (const float*)d_in[5];
    const float* Wr1   = (const float*)d_in[6];
    const float* br1   = (const float*)d_in[7];
    const float* Wr2   = (const float*)d_in[8];
    const float* br2   = (const float*)d_in[9];
    const float* Wtp   = (const float*)d_in[10];
    const float* btp   = (const float*)d_in[11];
    const float* Wm1   = (const float*)d_in[12];
    const float* bm1   = (const float*)d_in[13];
    const float* Wm2   = (const float*)d_in[14];
    const float* bm2   = (const float*)d_in[15];
    const float* Wqkv  = (const float*)d_in[16];
    const float* bqkv  = (const float*)d_in[17];
    const float* Wao   = (const float*)d_in[18];
    const float* bao   = (const float*)d_in[19];
    const float* Wg    = (const float*)d_in[20];
    const float* bg    = (const float*)d_in[21];
    const float* Wo    = (const float*)d_in[22];
    const float* bo    = (const float*)d_in[23];

    // workspace layout (floats), extent 4,456,448 f = 17.83 MB (R1-proven):
    float* ws    = (float*)d_ws;
    float* agg   = ws;                       // [0, 262144)
    float* comb  = agg  + N_ATOMS * 64;      // [262144, 786432)
    float* h1    = comb + N_ATOMS * 128;     // [786432, 1310720)
    float* upd   = h1   + N_ATOMS * 128;     // [1310720, 1835008)
    float* qkvf  = upd  + N_ATOMS * 128;     // [1835008, 3407872)
    float* attd  = qkvf + N_ATOMS * 384;     // [3407872, 3932160)
    float* aob   = attd + N_ATOMS * 128;     // [3932160, 4456448)
    // time-disjoint aliases:
    float* Wsl   = aob;                      // 73728 f; wprep(t0)->edge(t1); aob written t7
    float* outp  = comb;                     // comb last read at gemm m1 (t3)

    hipMemsetAsync(agg, 0, N_ATOMS * 64 * sizeof(float), stream);

    wprep_kernel<<<288, 256, 0, stream>>>(Wtp, Wsl);

    edge_kernel<<<N_EDGES / 64, 256, 0, stream>>>(
        evec, elen, eidx, Wr1, br1, Wr2, br2, Wsl, btp, agg);

    combined_kernel<<<(N_ATOMS * 64) / 256, 256, 0, stream>>>(an, emb, agg, comb);

    gemm128<1><<<dim3(64, 2), 256, 0, stream>>>(comb, Wm1, bm1, h1, 128, nullptr, nullptr);
    gemm128<0><<<dim3(64, 2), 256, 0, stream>>>(h1, Wm2, bm2, upd, 128, nullptr, nullptr);
    gemm128<0><<<dim3(64, 6), 256, 0, stream>>>(upd, Wqkv, bqkv, qkvf, 384, nullptr, nullptr);

    attn_kernel<<<1024, 256, 0, stream>>>(qkvf, attd);

    gemm128<0><<<dim3(64, 2), 256, 0, stream>>>(attd, Wao, bao, aob, 128, nullptr, nullptr);
    gemm128<2><<<dim3(64, 2), 256, 0, stream>>>(upd, Wg, bg, outp, 128, aob, upd);
    gemm128<0><<<dim3(64, 2), 256, 0, stream>>>(outp, Wo, bo, (float*)d_out, 128, nullptr, nullptr);
}

// Round 7
// 507.039 us; speedup vs baseline: 2.2444x; 2.2444x over previous
//
#include <hip/hip_runtime.h>
#include <hip/hip_bf16.h>
#include <math.h>

#define N_ATOMS 4096
#define N_EDGES 131072
#define PI6 0.52359877559829887308f

typedef __attribute__((ext_vector_type(4))) float f32x4;

__device__ __forceinline__ float silu_f(float x) { return x / (1.0f + __expf(-x)); }

// ---------------------------------------------------------------------------
// W-prep (f32): gather W_tp (only first 64 out-cols used downstream) into
// Wsl[f][o], f = s*128+c in [0,1152), o in [0,64). row(s,c) per reference.
// ---------------------------------------------------------------------------
__global__ void wprep_kernel(const float* __restrict__ Wtp, float* __restrict__ Wsl)
{
    int idx = blockIdx.x * 256 + threadIdx.x;     // < 9*128*64 = 73728
    int o = idx & 63;
    int c = (idx >> 6) & 127;
    int s = idx >> 13;
    int row = (s == 0) ? c : (s < 4 ? 128 + c * 3 + (s - 1) : 512 + c * 5 + (s - 4));
    Wsl[idx] = Wtp[row * 128 + o];
}

// ---------------------------------------------------------------------------
// Counting sort of edges by dst (order within dst nondeterministic -> only
// ulp-level float variation downstream).
// ---------------------------------------------------------------------------
__global__ void count_kernel(const int* __restrict__ eidx, int* __restrict__ deg)
{
    int e = blockIdx.x * 256 + threadIdx.x;
    atomicAdd(&deg[eidx[N_EDGES + e]], 1);
}

__global__ void scan_kernel(const int* __restrict__ deg, int* __restrict__ base,
                            int* __restrict__ cur)
{
    __shared__ int sums[1024];
    const int t = threadIdx.x;
    int v0 = deg[4*t], v1 = deg[4*t+1], v2 = deg[4*t+2], v3 = deg[4*t+3];
    int s = v0 + v1 + v2 + v3;
    sums[t] = s;
    __syncthreads();
    for (int off = 1; off < 1024; off <<= 1) {
        int x = (t >= off) ? sums[t - off] : 0;
        __syncthreads();
        sums[t] += x;
        __syncthreads();
    }
    int excl = (t > 0) ? sums[t - 1] : 0;
    base[4*t]   = excl;             cur[4*t]   = excl;
    base[4*t+1] = excl + v0;        cur[4*t+1] = excl + v0;
    base[4*t+2] = excl + v0 + v1;   cur[4*t+2] = excl + v0 + v1;
    base[4*t+3] = excl + v0 + v1 + v2; cur[4*t+3] = excl + v0 + v1 + v2;
}

__global__ void scatter_kernel(const int* __restrict__ eidx, int* __restrict__ cur,
                               int* __restrict__ sortedE)
{
    int e = blockIdx.x * 256 + threadIdx.x;
    int dst = eidx[N_EDGES + e];
    int p = atomicAdd(&cur[dst], 1);
    sortedE[p] = e;
}

// ---------------------------------------------------------------------------
// Aggregation kernel: one block (128 thr) per dst atom.
//  Per 4-edge chunk: rbf/sh (few threads) -> R1 (128x2 tasks) -> R2 per
//  channel (thread t = channel k) shared-W loads -> G[s] += sh_s*R2 (regs).
//  Then matvec agg[dst][o] = sum_f G[f]*Wsl[f][o] + deg*btp[o]. No atomics.
// ---------------------------------------------------------------------------
__global__ __launch_bounds__(128) void agg_kernel(
    const float* __restrict__ evec, const float* __restrict__ elen,
    const int* __restrict__ sortedE, const int* __restrict__ base,
    const int* __restrict__ deg,
    const float* __restrict__ Wr1, const float* __restrict__ br1,
    const float* __restrict__ Wr2, const float* __restrict__ br2,
    const float* __restrict__ Wsl, const float* __restrict__ btp,
    float* __restrict__ agg)
{
    __shared__ float rbfL[4][8];
    __shared__ float shL[4][9];
    __shared__ __align__(16) float R1L[4][64];
    __shared__ __align__(16) float GL[1152];
    __shared__ __align__(16) float redL[8][64];

    const int t = threadIdx.x;
    const int dst = blockIdx.x;
    const int dg = deg[dst];
    const int bs = base[dst];

    float G[9] = {0.f,0.f,0.f,0.f,0.f,0.f,0.f,0.f,0.f};

    const int nch = (dg + 3) >> 2;
    for (int c = 0; c < nch; ++c) {
        __syncthreads();   // protect LDS reuse across chunks
        // ---- stage rbf (threads 0..31) and sh (threads 32..35) ----
        if (t < 32) {
            int el = t >> 3, f = t & 7;
            int ce = c * 4 + el;
            float v = 0.f;
            if (ce < dg) {
                int eid = sortedE[bs + ce];
                float len = elen[eid];
                float env = 0.5f * (cosf(len * PI6) + 1.0f) * (len < 6.0f ? 1.0f : 0.0f);
                v = sinf(len * ((float)(f + 1) * PI6)) * (env / len);
            }
            rbfL[el][f] = v;
        } else if (t < 36) {
            int el = t - 32;
            int ce = c * 4 + el;
            float s0=0,s1=0,s2=0,s3=0,s4=0,s5=0,s6=0,s7=0,s8=0;
            if (ce < dg) {
                int eid = sortedE[bs + ce];
                float vx = evec[eid*3], vy = evec[eid*3+1], vz = evec[eid*3+2];
                float r = sqrtf(vx*vx + vy*vy + vz*vz) + 1e-8f;
                float inv = 1.0f / r;
                float x = vx*inv, y = vy*inv, z = vz*inv;
                s0 = 1.0f; s1 = y; s2 = z; s3 = x;
                s4 = 3.0f*z*z - 1.0f; s5 = x*z; s6 = y*z; s7 = x*y; s8 = x*x - y*y;
            }
            shL[el][0]=s0; shL[el][1]=s1; shL[el][2]=s2; shL[el][3]=s3;
            shL[el][4]=s4; shL[el][5]=s5; shL[el][6]=s6; shL[el][7]=s7; shL[el][8]=s8;
        }
        __syncthreads();
        // ---- R1: 256 tasks over 128 threads ----
        #pragma unroll
        for (int rep = 0; rep < 2; ++rep) {
            int tau = t + rep * 128;
            int el = tau >> 6, ko = tau & 63;
            float acc = br1[ko];
            #pragma unroll
            for (int f = 0; f < 8; ++f)
                acc = fmaf(rbfL[el][f], Wr1[f * 64 + ko], acc);
            R1L[el][ko] = silu_f(acc);
        }
        __syncthreads();
        // ---- R2 (thread t = channel) + G accumulate ----
        float a0 = 0.f, a1 = 0.f, a2 = 0.f, a3 = 0.f;
        for (int j = 0; j < 64; ++j) {
            float w = Wr2[j * 128 + t];
            a0 = fmaf(R1L[0][j], w, a0);
            a1 = fmaf(R1L[1][j], w, a1);
            a2 = fmaf(R1L[2][j], w, a2);
            a3 = fmaf(R1L[3][j], w, a3);
        }
        float b2 = br2[t];
        int rem = dg - c * 4;
        if (rem > 0) { float r2 = silu_f(a0 + b2);
            #pragma unroll
            for (int s2 = 0; s2 < 9; ++s2) G[s2] = fmaf(shL[0][s2], r2, G[s2]); }
        if (rem > 1) { float r2 = silu_f(a1 + b2);
            #pragma unroll
            for (int s2 = 0; s2 < 9; ++s2) G[s2] = fmaf(shL[1][s2], r2, G[s2]); }
        if (rem > 2) { float r2 = silu_f(a2 + b2);
            #pragma unroll
            for (int s2 = 0; s2 < 9; ++s2) G[s2] = fmaf(shL[2][s2], r2, G[s2]); }
        if (rem > 3) { float r2 = silu_f(a3 + b2);
            #pragma unroll
            for (int s2 = 0; s2 < 9; ++s2) G[s2] = fmaf(shL[3][s2], r2, G[s2]); }
    }

    // ---- matvec: agg[dst][o] = sum_f GL[f]*Wsl[f][o] + dg*btp[o] ----
    #pragma unroll
    for (int s2 = 0; s2 < 9; ++s2) GL[s2 * 128 + t] = G[s2];
    __syncthreads();

    const f32x4* Wsl4 = (const f32x4*)Wsl;
    const int og = (t & 15) * 4;
    const int q  = t >> 4;              // 8 f-ranges of 144
    f32x4 acc4 = {0.f, 0.f, 0.f, 0.f};
    for (int i = 0; i < 144; ++i) {
        int f = q * 144 + i;
        float g = GL[f];
        f32x4 w = Wsl4[f * 16 + (t & 15)];
        acc4 = acc4 + w * g;
    }
    *(f32x4*)&redL[q][og] = acc4;
    __syncthreads();
    if (t < 64) {
        float sum = 0.f;
        #pragma unroll
        for (int q2 = 0; q2 < 8; ++q2) sum += redL[q2][t];
        agg[dst * 64 + t] = sum + (float)dg * btp[t];
    }
}

// ---------------------------------------------------------------------------
__global__ void combined_kernel(const int* __restrict__ an,
                                const float* __restrict__ emb,
                                const float* __restrict__ agg,
                                float* __restrict__ comb)
{
    int i = blockIdx.x * 256 + threadIdx.x;
    if (i < N_ATOMS * 64) {
        int n = i >> 6, d = i & 63;
        comb[n * 128 + d]      = emb[an[n] * 64 + d];
        comb[n * 128 + 64 + d] = agg[n * 64 + d];
    }
}

// ---------------------------------------------------------------------------
template <int ACT>
__global__ __launch_bounds__(256, 2) void gemm128(
    const float* __restrict__ A, const float* __restrict__ W,
    const float* __restrict__ bias, float* __restrict__ C, int N,
    const float* __restrict__ aux1, const float* __restrict__ aux2)
{
    __shared__ __align__(16) float AT[128][64];
    __shared__ __align__(16) float Ws[128][64];
    const int t  = threadIdx.x;
    const int M0 = blockIdx.x * 64;
    const int N0 = blockIdx.y * 64;

    for (int idx = t; idx < 64 * 128; idx += 256) {
        int m = idx >> 7, k = idx & 127;
        AT[k][m ^ ((k & 15) << 2)] = A[(M0 + m) * 128 + k];
    }
    for (int idx = t; idx < 128 * 64; idx += 256) {
        int k = idx >> 6, o = idx & 63;
        Ws[k][o] = W[k * N + N0 + o];
    }
    __syncthreads();

    const int m0 = (t & 15) * 4;
    const int o0 = (t >> 4) * 4;
    float acc[4][4] = {};
    #pragma unroll 2
    for (int k = 0; k < 128; ++k) {
        int xs = (k & 15) << 2;
        float4 a4 = *(const float4*)&AT[k][m0 ^ xs];
        float4 w4 = *(const float4*)&Ws[k][o0];
        float av[4] = {a4.x, a4.y, a4.z, a4.w};
        float wv[4] = {w4.x, w4.y, w4.z, w4.w};
        #pragma unroll
        for (int i = 0; i < 4; ++i)
            #pragma unroll
            for (int j = 0; j < 4; ++j)
                acc[i][j] = fmaf(av[i], wv[j], acc[i][j]);
    }

    #pragma unroll
    for (int i = 0; i < 4; ++i) {
        int m = M0 + m0 + i;
        #pragma unroll
        for (int j = 0; j < 4; ++j) {
            int o = N0 + o0 + j;
            float v = acc[i][j] + bias[o];
            if (ACT == 1) v = silu_f(v);
            if (ACT == 2) {
                float sg = 1.0f / (1.0f + __expf(-v));
                v = sg * aux1[m * 128 + o] + (1.0f - sg) * aux2[m * 128 + o];
            }
            C[m * N + o] = v;
        }
    }
}

// ---------------------------------------------------------------------------
// f32 flash attention, thread = q-row. Block = (head, 32 q-rows), 256 thr:
// thread t: row = t&31, split s = t>>5 (8 splits x 512 m). K/V rows read
// from LDS with wave-uniform (broadcast) addresses -> no bank conflicts.
// Q[32], O[32] in registers. 16-m windows amortize the online rescale.
// LDS split-merge tree at the end.
// ---------------------------------------------------------------------------
__global__ __launch_bounds__(256) void attn_kernel(
    const float* __restrict__ qkv, float* __restrict__ attd)
{
    __shared__ __align__(16) float KVL[16384];   // K [0,8192) | V [8192,16384)

    const int t = threadIdx.x;
    const int r = t & 31, s = t >> 5;
    const int h = blockIdx.x >> 7, qc = blockIdx.x & 127;
    const int row = qc * 32 + r;
    const float scale = 0.17677669529663687f;    // 1/sqrt(32)

    f32x4 Qv[8], Ov[8];
    #pragma unroll
    for (int i = 0; i < 8; ++i) {
        Qv[i] = *(const f32x4*)(qkv + row * 384 + h * 32 + i * 4) * scale;
        Ov[i] = (f32x4){0.f, 0.f, 0.f, 0.f};
    }
    float m = -1e30f, l = 0.f;

    for (int T = 0; T < 16; ++T) {
        __syncthreads();
        // stage 32-m windows for all 8 splits (coalesced global float4)
        #pragma unroll
        for (int i = 0; i < 8; ++i) {
            int f4 = i * 256 + t;                 // [0,2048)
            int ss = f4 >> 8, rem = f4 & 255;
            int mm = rem >> 3, d4 = (rem & 7) * 4;
            const float* gp = qkv + (ss * 512 + T * 32 + mm) * 384 + h * 32;
            *(f32x4*)&KVL[f4 * 4]        = *(const f32x4*)(gp + 128 + d4);
            *(f32x4*)&KVL[8192 + f4 * 4] = *(const f32x4*)(gp + 256 + d4);
        }
        __syncthreads();

        const float* Kp = &KVL[s * 1024];
        const float* Vp = &KVL[8192 + s * 1024];
        #pragma unroll
        for (int half = 0; half < 2; ++half) {
            float Sv[16];
            #pragma unroll
            for (int mm = 0; mm < 16; ++mm) {
                const float* kr = Kp + (half * 16 + mm) * 32;
                float a0 = 0.f, a1 = 0.f, a2 = 0.f, a3 = 0.f;
                #pragma unroll
                for (int i = 0; i < 8; ++i) {
                    f32x4 kk = *(const f32x4*)(kr + i * 4);
                    a0 = fmaf(Qv[i][0], kk[0], a0);
                    a1 = fmaf(Qv[i][1], kk[1], a1);
                    a2 = fmaf(Qv[i][2], kk[2], a2);
                    a3 = fmaf(Qv[i][3], kk[3], a3);
                }
                Sv[mm] = (a0 + a1) + (a2 + a3);
            }
            float wmax = Sv[0];
            #pragma unroll
            for (int mm = 1; mm < 16; ++mm) wmax = fmaxf(wmax, Sv[mm]);
            float nm = fmaxf(m, wmax);
            float cc = __expf(m - nm);
            m = nm;
            l *= cc;
            #pragma unroll
            for (int i = 0; i < 8; ++i) Ov[i] *= cc;
            #pragma unroll
            for (int mm = 0; mm < 16; ++mm) {
                float p = __expf(Sv[mm] - nm);
                l += p;
                const float* vr = Vp + (half * 16 + mm) * 32;
                #pragma unroll
                for (int i = 0; i < 8; ++i) {
                    f32x4 vv = *(const f32x4*)(vr + i * 4);
                    Ov[i] = Ov[i] + vv * p;
                }
            }
        }
    }

    // ---- merge 8 splits ----
    __syncthreads();
    KVL[s * 32 + r] = m;
    __syncthreads();
    float M = KVL[r];
    #pragma unroll
    for (int q2 = 1; q2 < 8; ++q2) M = fmaxf(M, KVL[q2 * 32 + r]);
    float fsc = __expf(m - M);
    l *= fsc;
    #pragma unroll
    for (int i = 0; i < 8; ++i) Ov[i] *= fsc;
    __syncthreads();

    // tree slots: KVL[512 + (slot*32 + r)*36 ...], 33 floats used (O[32], l)
    #define TSLOT(sl) (&KVL[512 + (((sl) * 32 + r) * 36)])
    // round 1: odd s -> slot s>>1
    if (s & 1) {
        float* tb = TSLOT(s >> 1);
        #pragma unroll
        for (int i = 0; i < 8; ++i) *(f32x4*)(tb + i * 4) = Ov[i];
        tb[32] = l;
    }
    __syncthreads();
    if (!(s & 1)) {
        float* tb = TSLOT(s >> 1);
        #pragma unroll
        for (int i = 0; i < 8; ++i) Ov[i] = Ov[i] + *(const f32x4*)(tb + i * 4);
        l += tb[32];
    }
    __syncthreads();
    // round 2: s in {2,6} -> slot s>>2
    if ((s & 3) == 2) {
        float* tb = TSLOT(s >> 2);
        #pragma unroll
        for (int i = 0; i < 8; ++i) *(f32x4*)(tb + i * 4) = Ov[i];
        tb[32] = l;
    }
    __syncthreads();
    if ((s & 3) == 0) {
        float* tb = TSLOT(s >> 2);
        #pragma unroll
        for (int i = 0; i < 8; ++i) Ov[i] = Ov[i] + *(const f32x4*)(tb + i * 4);
        l += tb[32];
    }
    __syncthreads();
    // round 3: s==4 -> slot 0, s==0 reads
    if (s == 4) {
        float* tb = TSLOT(0);
        #pragma unroll
        for (int i = 0; i < 8; ++i) *(f32x4*)(tb + i * 4) = Ov[i];
        tb[32] = l;
    }
    __syncthreads();
    if (s == 0) {
        float* tb = TSLOT(0);
        #pragma unroll
        for (int i = 0; i < 8; ++i) Ov[i] = Ov[i] + *(const f32x4*)(tb + i * 4);
        l += tb[32];
        float inv = 1.0f / l;
        #pragma unroll
        for (int i = 0; i < 8; ++i)
            *(f32x4*)(attd + row * 128 + h * 32 + i * 4) = Ov[i] * inv;
    }
    #undef TSLOT
}

// ---------------------------------------------------------------------------
extern "C" void kernel_launch(void* const* d_in, const int* in_sizes, int n_in,
                              void* d_out, int out_size, void* d_ws, size_t ws_size,
                              hipStream_t stream) {
    const int*   an    = (const int*)d_in[0];
    const int*   eidx  = (const int*)d_in[2];
    const float* evec  = (const float*)d_in[3];
    const float* elen  = (const float*)d_in[4];
    const float* emb   = (const float*)d_in[5];
    const float* Wr1   = (const float*)d_in[6];
    const float* br1   = (const float*)d_in[7];
    const float* Wr2   = (const float*)d_in[8];
    const float* br2   = (const float*)d_in[9];
    const float* Wtp   = (const float*)d_in[10];
    const float* btp   = (const float*)d_in[11];
    const float* Wm1   = (const float*)d_in[12];
    const float* bm1   = (const float*)d_in[13];
    const float* Wm2   = (const float*)d_in[14];
    const float* bm2   = (const float*)d_in[15];
    const float* Wqkv  = (const float*)d_in[16];
    const float* bqkv  = (const float*)d_in[17];
    const float* Wao   = (const float*)d_in[18];
    const float* bao   = (const float*)d_in[19];
    const float* Wg    = (const float*)d_in[20];
    const float* bg    = (const float*)d_in[21];
    const float* Wo    = (const float*)d_in[22];
    const float* bo    = (const float*)d_in[23];

    // workspace layout (floats), extent 4,456,448 f = 17.83 MB (R6-proven):
    float* ws    = (float*)d_ws;
    float* agg   = ws;                       // [0, 262144)
    float* comb  = agg  + N_ATOMS * 64;      // [262144, 786432)
    float* h1    = comb + N_ATOMS * 128;     // [786432, 1310720)
    float* upd   = h1   + N_ATOMS * 128;     // [1310720, 1835008)
    float* qkvf  = upd  + N_ATOMS * 128;     // [1835008, 3407872)
    float* attd  = qkvf + N_ATOMS * 384;     // [3407872, 3932160)
    float* aob   = attd + N_ATOMS * 128;     // [3932160, 4456448)
    // time-disjoint aliases:
    float* Wsl   = aob;                      // 73728 f; used t4..t5; aob written t11
    float* outp  = comb;                     // comb last read at gemm m1
    // sort scratch inside attd region (dead until attn writes it):
    int* deg     = (int*)attd;               // 4096
    int* base    = deg + 4096;               // 4096
    int* cur     = base + 4096;              // 4096
    int* sortedE = cur + 4096;               // 131072  (total 143360 < 524288)

    hipMemsetAsync(deg, 0, 4096 * sizeof(int), stream);

    count_kernel<<<512, 256, 0, stream>>>(eidx, deg);
    scan_kernel<<<1, 1024, 0, stream>>>(deg, base, cur);
    scatter_kernel<<<512, 256, 0, stream>>>(eidx, cur, sortedE);

    wprep_kernel<<<288, 256, 0, stream>>>(Wtp, Wsl);

    agg_kernel<<<N_ATOMS, 128, 0, stream>>>(
        evec, elen, sortedE, base, deg, Wr1, br1, Wr2, br2, Wsl, btp, agg);

    combined_kernel<<<(N_ATOMS * 64) / 256, 256, 0, stream>>>(an, emb, agg, comb);

    gemm128<1><<<dim3(64, 2), 256, 0, stream>>>(comb, Wm1, bm1, h1, 128, nullptr, nullptr);
    gemm128<0><<<dim3(64, 2), 256, 0, stream>>>(h1, Wm2, bm2, upd, 128, nullptr, nullptr);
    gemm128<0><<<dim3(64, 6), 256, 0, stream>>>(upd, Wqkv, bqkv, qkvf, 384, nullptr, nullptr);

    attn_kernel<<<512, 256, 0, stream>>>(qkvf, attd);

    gemm128<0><<<dim3(64, 2), 256, 0, stream>>>(attd, Wao, bao, aob, 128, nullptr, nullptr);
    gemm128<2><<<dim3(64, 2), 256, 0, stream>>>(upd, Wg, bg, outp, 128, aob, upd);
    gemm128<0><<<dim3(64, 2), 256, 0, stream>>>(outp, Wo, bo, (float*)d_out, 128, nullptr, nullptr);
}

// Round 8
// 298.744 us; speedup vs baseline: 3.8092x; 1.6972x over previous
//
#include <hip/hip_runtime.h>
#include <hip/hip_bf16.h>
#include <math.h>

#define N_ATOMS 4096
#define N_EDGES 131072
#define PI6 0.52359877559829887308f

typedef __attribute__((ext_vector_type(4))) float f32x4;
typedef _Float16 h16;
typedef __attribute__((ext_vector_type(8))) _Float16 half8;

__device__ __forceinline__ float silu_f(float x) { return x / (1.0f + __expf(-x)); }

__device__ __forceinline__ unsigned pk2h(float lo, float hi) {
    h16 a = (h16)lo, b = (h16)hi;
    unsigned short ua, ub;
    __builtin_memcpy(&ua, &a, 2);
    __builtin_memcpy(&ub, &b, 2);
    return ((unsigned)ub << 16) | (unsigned)ua;
}

// ---------------------------------------------------------------------------
// W-prep (f32): gather W_tp (only first 64 out-cols used downstream) into
// Wsl[f][o], f = s*128+c in [0,1152), o in [0,64). row(s,c) per reference.
// ---------------------------------------------------------------------------
__global__ void wprep_kernel(const float* __restrict__ Wtp, float* __restrict__ Wsl)
{
    int idx = blockIdx.x * 256 + threadIdx.x;     // < 9*128*64 = 73728
    int o = idx & 63;
    int c = (idx >> 6) & 127;
    int s = idx >> 13;
    int row = (s == 0) ? c : (s < 4 ? 128 + c * 3 + (s - 1) : 512 + c * 5 + (s - 4));
    Wsl[idx] = Wtp[row * 128 + o];
}

// ---------------------------------------------------------------------------
// Counting sort of edges by dst.
// ---------------------------------------------------------------------------
__global__ void count_kernel(const int* __restrict__ eidx, int* __restrict__ deg)
{
    int e = blockIdx.x * 256 + threadIdx.x;
    atomicAdd(&deg[eidx[N_EDGES + e]], 1);
}

__global__ void scan_kernel(const int* __restrict__ deg, int* __restrict__ base,
                            int* __restrict__ cur)
{
    __shared__ int sums[1024];
    const int t = threadIdx.x;
    int v0 = deg[4*t], v1 = deg[4*t+1], v2 = deg[4*t+2], v3 = deg[4*t+3];
    int s = v0 + v1 + v2 + v3;
    sums[t] = s;
    __syncthreads();
    for (int off = 1; off < 1024; off <<= 1) {
        int x = (t >= off) ? sums[t - off] : 0;
        __syncthreads();
        sums[t] += x;
        __syncthreads();
    }
    int excl = (t > 0) ? sums[t - 1] : 0;
    base[4*t]   = excl;             cur[4*t]   = excl;
    base[4*t+1] = excl + v0;        cur[4*t+1] = excl + v0;
    base[4*t+2] = excl + v0 + v1;   cur[4*t+2] = excl + v0 + v1;
    base[4*t+3] = excl + v0 + v1 + v2; cur[4*t+3] = excl + v0 + v1 + v2;
}

__global__ void scatter_kernel(const int* __restrict__ eidx, int* __restrict__ cur,
                               int* __restrict__ sortedE)
{
    int e = blockIdx.x * 256 + threadIdx.x;
    int dst = eidx[N_EDGES + e];
    int p = atomicAdd(&cur[dst], 1);
    sortedE[p] = e;
}

// ---------------------------------------------------------------------------
// Aggregation kernel: one block (128 thr) per dst atom. All f32, no atomics.
// ---------------------------------------------------------------------------
__global__ __launch_bounds__(128) void agg_kernel(
    const float* __restrict__ evec, const float* __restrict__ elen,
    const int* __restrict__ sortedE, const int* __restrict__ base,
    const int* __restrict__ deg,
    const float* __restrict__ Wr1, const float* __restrict__ br1,
    const float* __restrict__ Wr2, const float* __restrict__ br2,
    const float* __restrict__ Wsl, const float* __restrict__ btp,
    float* __restrict__ agg)
{
    __shared__ float rbfL[4][8];
    __shared__ float shL[4][9];
    __shared__ __align__(16) float R1L[4][64];
    __shared__ __align__(16) float GL[1152];
    __shared__ __align__(16) float redL[8][64];

    const int t = threadIdx.x;
    const int dst = blockIdx.x;
    const int dg = deg[dst];
    const int bs = base[dst];

    float G[9] = {0.f,0.f,0.f,0.f,0.f,0.f,0.f,0.f,0.f};

    const int nch = (dg + 3) >> 2;
    for (int c = 0; c < nch; ++c) {
        __syncthreads();
        if (t < 32) {
            int el = t >> 3, f = t & 7;
            int ce = c * 4 + el;
            float v = 0.f;
            if (ce < dg) {
                int eid = sortedE[bs + ce];
                float len = elen[eid];
                float env = 0.5f * (cosf(len * PI6) + 1.0f) * (len < 6.0f ? 1.0f : 0.0f);
                v = sinf(len * ((float)(f + 1) * PI6)) * (env / len);
            }
            rbfL[el][f] = v;
        } else if (t < 36) {
            int el = t - 32;
            int ce = c * 4 + el;
            float s0=0,s1=0,s2=0,s3=0,s4=0,s5=0,s6=0,s7=0,s8=0;
            if (ce < dg) {
                int eid = sortedE[bs + ce];
                float vx = evec[eid*3], vy = evec[eid*3+1], vz = evec[eid*3+2];
                float r = sqrtf(vx*vx + vy*vy + vz*vz) + 1e-8f;
                float inv = 1.0f / r;
                float x = vx*inv, y = vy*inv, z = vz*inv;
                s0 = 1.0f; s1 = y; s2 = z; s3 = x;
                s4 = 3.0f*z*z - 1.0f; s5 = x*z; s6 = y*z; s7 = x*y; s8 = x*x - y*y;
            }
            shL[el][0]=s0; shL[el][1]=s1; shL[el][2]=s2; shL[el][3]=s3;
            shL[el][4]=s4; shL[el][5]=s5; shL[el][6]=s6; shL[el][7]=s7; shL[el][8]=s8;
        }
        __syncthreads();
        #pragma unroll
        for (int rep = 0; rep < 2; ++rep) {
            int tau = t + rep * 128;
            int el = tau >> 6, ko = tau & 63;
            float acc = br1[ko];
            #pragma unroll
            for (int f = 0; f < 8; ++f)
                acc = fmaf(rbfL[el][f], Wr1[f * 64 + ko], acc);
            R1L[el][ko] = silu_f(acc);
        }
        __syncthreads();
        float a0 = 0.f, a1 = 0.f, a2 = 0.f, a3 = 0.f;
        for (int j = 0; j < 64; ++j) {
            float w = Wr2[j * 128 + t];
            a0 = fmaf(R1L[0][j], w, a0);
            a1 = fmaf(R1L[1][j], w, a1);
            a2 = fmaf(R1L[2][j], w, a2);
            a3 = fmaf(R1L[3][j], w, a3);
        }
        float b2 = br2[t];
        int rem = dg - c * 4;
        if (rem > 0) { float r2 = silu_f(a0 + b2);
            #pragma unroll
            for (int s2 = 0; s2 < 9; ++s2) G[s2] = fmaf(shL[0][s2], r2, G[s2]); }
        if (rem > 1) { float r2 = silu_f(a1 + b2);
            #pragma unroll
            for (int s2 = 0; s2 < 9; ++s2) G[s2] = fmaf(shL[1][s2], r2, G[s2]); }
        if (rem > 2) { float r2 = silu_f(a2 + b2);
            #pragma unroll
            for (int s2 = 0; s2 < 9; ++s2) G[s2] = fmaf(shL[2][s2], r2, G[s2]); }
        if (rem > 3) { float r2 = silu_f(a3 + b2);
            #pragma unroll
            for (int s2 = 0; s2 < 9; ++s2) G[s2] = fmaf(shL[3][s2], r2, G[s2]); }
    }

    #pragma unroll
    for (int s2 = 0; s2 < 9; ++s2) GL[s2 * 128 + t] = G[s2];
    __syncthreads();

    const f32x4* Wsl4 = (const f32x4*)Wsl;
    const int og = (t & 15) * 4;
    const int q  = t >> 4;
    f32x4 acc4 = {0.f, 0.f, 0.f, 0.f};
    for (int i = 0; i < 144; ++i) {
        int f = q * 144 + i;
        float g = GL[f];
        f32x4 w = Wsl4[f * 16 + (t & 15)];
        acc4 = acc4 + w * g;
    }
    *(f32x4*)&redL[q][og] = acc4;
    __syncthreads();
    if (t < 64) {
        float sum = 0.f;
        #pragma unroll
        for (int q2 = 0; q2 < 8; ++q2) sum += redL[q2][t];
        agg[dst * 64 + t] = sum + (float)dg * btp[t];
    }
}

// ---------------------------------------------------------------------------
__global__ void combined_kernel(const int* __restrict__ an,
                                const float* __restrict__ emb,
                                const float* __restrict__ agg,
                                float* __restrict__ comb)
{
    int i = blockIdx.x * 256 + threadIdx.x;
    if (i < N_ATOMS * 64) {
        int n = i >> 6, d = i & 63;
        comb[n * 128 + d]      = emb[an[n] * 64 + d];
        comb[n * 128 + 64 + d] = agg[n * 64 + d];
    }
}

// ---------------------------------------------------------------------------
template <int ACT>
__global__ __launch_bounds__(256, 2) void gemm128(
    const float* __restrict__ A, const float* __restrict__ W,
    const float* __restrict__ bias, float* __restrict__ C, int N,
    const float* __restrict__ aux1, const float* __restrict__ aux2)
{
    __shared__ __align__(16) float AT[128][64];
    __shared__ __align__(16) float Ws[128][64];
    const int t  = threadIdx.x;
    const int M0 = blockIdx.x * 64;
    const int N0 = blockIdx.y * 64;

    for (int idx = t; idx < 64 * 128; idx += 256) {
        int m = idx >> 7, k = idx & 127;
        AT[k][m ^ ((k & 15) << 2)] = A[(M0 + m) * 128 + k];
    }
    for (int idx = t; idx < 128 * 64; idx += 256) {
        int k = idx >> 6, o = idx & 63;
        Ws[k][o] = W[k * N + N0 + o];
    }
    __syncthreads();

    const int m0 = (t & 15) * 4;
    const int o0 = (t >> 4) * 4;
    float acc[4][4] = {};
    #pragma unroll 2
    for (int k = 0; k < 128; ++k) {
        int xs = (k & 15) << 2;
        float4 a4 = *(const float4*)&AT[k][m0 ^ xs];
        float4 w4 = *(const float4*)&Ws[k][o0];
        float av[4] = {a4.x, a4.y, a4.z, a4.w};
        float wv[4] = {w4.x, w4.y, w4.z, w4.w};
        #pragma unroll
        for (int i = 0; i < 4; ++i)
            #pragma unroll
            for (int j = 0; j < 4; ++j)
                acc[i][j] = fmaf(av[i], wv[j], acc[i][j]);
    }

    #pragma unroll
    for (int i = 0; i < 4; ++i) {
        int m = M0 + m0 + i;
        #pragma unroll
        for (int j = 0; j < 4; ++j) {
            int o = N0 + o0 + j;
            float v = acc[i][j] + bias[o];
            if (ACT == 1) v = silu_f(v);
            if (ACT == 2) {
                float sg = 1.0f / (1.0f + __expf(-v));
                v = sg * aux1[m * 128 + o] + (1.0f - sg) * aux2[m * 128 + o];
            }
            C[m * N + o] = v;
        }
    }
}

// ---------------------------------------------------------------------------
// qkv f32 -> fp16 prep: Qh/Kh [h][n][32] (Q pre-scaled), VT [h][32d][4096n]
// ---------------------------------------------------------------------------
__global__ void qkprep_kernel(const float* __restrict__ qkvf,
                              h16* __restrict__ Qh, h16* __restrict__ Kh)
{
    int i = blockIdx.x * 256 + threadIdx.x;       // < 4*4096*32
    int d = i & 31, n = (i >> 5) & 4095, h = i >> 17;
    Qh[(h * 4096 + n) * 32 + d] = (h16)(qkvf[n * 384 + h * 32 + d] * 0.17677669529663687f);
    Kh[(h * 4096 + n) * 32 + d] = (h16)(qkvf[n * 384 + 128 + h * 32 + d]);
}

__global__ void vtprep_kernel(const float* __restrict__ qkvf,
                              h16* __restrict__ VT)
{
    int i = blockIdx.x * 256 + threadIdx.x;       // < 128*4096
    int n = i & 4095, dh = i >> 12;               // dh = h*32+d
    VT[dh * 4096 + n] = (h16)qkvf[n * 384 + 256 + dh];
}

// ---------------------------------------------------------------------------
// Flash attention, fp16 MFMA, LDS-free main loop (R4 structure, validated).
// Block = (head, 16-row q-tile); 4 waves split KV 4-way; LDS merge at end.
// ---------------------------------------------------------------------------
__global__ __launch_bounds__(256, 4) void attn_kernel(
    const h16* __restrict__ Qh, const h16* __restrict__ Kh,
    const h16* __restrict__ VT, float* __restrict__ attd)
{
    __shared__ float st[4][64][10];
    const int t = threadIdx.x, w = t >> 6, lane = t & 63;
    const int h = blockIdx.x >> 8, qt = blockIdx.x & 255;
    const int l15 = lane & 15, g = lane >> 4;

    const h16* Kb = Kh + (size_t)h * 4096 * 32;
    const h16* Vb = VT + (size_t)h * 32 * 4096;
    half8 Qf = *(const half8*)(Qh + ((size_t)(h * 4096 + qt * 16 + l15) * 32 + g * 8));

    float m = -1e30f, l = 0.0f;
    f32x4 O0 = {0.f,0.f,0.f,0.f}, O1 = {0.f,0.f,0.f,0.f};
    const f32x4 zf = {0.f,0.f,0.f,0.f};
    const int sAlane = l15 + ((g & 1) << 5);
    const bool hi = g >= 2;

    const int kvbase = w * 1024;
    for (int kt = 0; kt < 32; ++kt) {
        int kv0 = kvbase + kt * 32;
        half8 K0 = *(const half8*)(Kb + ((size_t)(kv0 + l15) * 32 + g * 8));
        half8 K1 = *(const half8*)(Kb + ((size_t)(kv0 + 16 + l15) * 32 + g * 8));
        f32x4 S0 = __builtin_amdgcn_mfma_f32_16x16x32_f16(K0, Qf, zf, 0, 0, 0);
        f32x4 S1 = __builtin_amdgcn_mfma_f32_16x16x32_f16(K1, Qf, zf, 0, 0, 0);

        float tmax = fmaxf(fmaxf(fmaxf(S0.x, S0.y), fmaxf(S0.z, S0.w)),
                           fmaxf(fmaxf(S1.x, S1.y), fmaxf(S1.z, S1.w)));
        tmax = fmaxf(tmax, __shfl_xor(tmax, 16));
        tmax = fmaxf(tmax, __shfl_xor(tmax, 32));
        float mn = fmaxf(m, tmax);
        float c = __expf(m - mn);
        m = mn;
        float p0[4], p1[4];
        float ts = 0.f;
        #pragma unroll
        for (int i = 0; i < 4; ++i) { p0[i] = __expf(S0[i] - mn); ts += p0[i]; }
        #pragma unroll
        for (int i = 0; i < 4; ++i) { p1[i] = __expf(S1[i] - mn); ts += p1[i]; }
        ts += __shfl_xor(ts, 16);
        ts += __shfl_xor(ts, 32);
        l = l * c + ts;
        #pragma unroll
        for (int i = 0; i < 4; ++i) { O0[i] *= c; O1[i] *= c; }

        unsigned A0 = pk2h(p0[0], p0[1]), A1 = pk2h(p0[2], p0[3]);
        unsigned A2 = pk2h(p1[0], p1[1]), A3 = pk2h(p1[2], p1[3]);
        unsigned t0 = (unsigned)__shfl((int)A0, sAlane);
        unsigned t1 = (unsigned)__shfl((int)A1, sAlane);
        unsigned t2 = (unsigned)__shfl((int)A2, sAlane);
        unsigned t3 = (unsigned)__shfl((int)A3, sAlane);
        unsigned u0 = (unsigned)__shfl((int)A0, sAlane + 16);
        unsigned u1 = (unsigned)__shfl((int)A1, sAlane + 16);
        unsigned u2 = (unsigned)__shfl((int)A2, sAlane + 16);
        unsigned u3 = (unsigned)__shfl((int)A3, sAlane + 16);
        union { unsigned u[4]; half8 v; } P;
        P.u[0] = hi ? t2 : t0;
        P.u[1] = hi ? t3 : t1;
        P.u[2] = hi ? u2 : u0;
        P.u[3] = hi ? u3 : u1;

        half8 V0 = *(const half8*)(Vb + ((size_t)l15 * 4096 + kv0 + g * 8));
        half8 V1 = *(const half8*)(Vb + ((size_t)(16 + l15) * 4096 + kv0 + g * 8));
        O0 = __builtin_amdgcn_mfma_f32_16x16x32_f16(V0, P.v, O0, 0, 0, 0);
        O1 = __builtin_amdgcn_mfma_f32_16x16x32_f16(V1, P.v, O1, 0, 0, 0);
    }

    #pragma unroll
    for (int i = 0; i < 4; ++i) { st[w][lane][i] = O0[i]; st[w][lane][4 + i] = O1[i]; }
    st[w][lane][8] = m;
    st[w][lane][9] = l;
    __syncthreads();

    if (w == 0) {
        float M = -1e30f;
        #pragma unroll
        for (int j = 0; j < 4; ++j) M = fmaxf(M, st[j][lane][8]);
        float L = 0.f, o0[4] = {}, o1[4] = {};
        #pragma unroll
        for (int j = 0; j < 4; ++j) {
            float f = __expf(st[j][lane][8] - M);
            L += st[j][lane][9] * f;
            #pragma unroll
            for (int i = 0; i < 4; ++i) {
                o0[i] = fmaf(st[j][lane][i], f, o0[i]);
                o1[i] = fmaf(st[j][lane][4 + i], f, o1[i]);
            }
        }
        float invL = 1.0f / L;
        int nq = qt * 16 + l15;
        #pragma unroll
        for (int i = 0; i < 4; ++i) {
            attd[nq * 128 + h * 32 + g * 4 + i]      = o0[i] * invL;
            attd[nq * 128 + h * 32 + 16 + g * 4 + i] = o1[i] * invL;
        }
    }
}

// ---------------------------------------------------------------------------
extern "C" void kernel_launch(void* const* d_in, const int* in_sizes, int n_in,
                              void* d_out, int out_size, void* d_ws, size_t ws_size,
                              hipStream_t stream) {
    const int*   an    = (const int*)d_in[0];
    const int*   eidx  = (const int*)d_in[2];
    const float* evec  = (const float*)d_in[3];
    const float* elen  = (const float*)d_in[4];
    const float* emb   = (const float*)d_in[5];
    const float* Wr1   = (const float*)d_in[6];
    const float* br1   = (const float*)d_in[7];
    const float* Wr2   = (const float*)d_in[8];
    const float* br2   = (const float*)d_in[9];
    const float* Wtp   = (const float*)d_in[10];
    const float* btp   = (const float*)d_in[11];
    const float* Wm1   = (const float*)d_in[12];
    const float* bm1   = (const float*)d_in[13];
    const float* Wm2   = (const float*)d_in[14];
    const float* bm2   = (const float*)d_in[15];
    const float* Wqkv  = (const float*)d_in[16];
    const float* bqkv  = (const float*)d_in[17];
    const float* Wao   = (const float*)d_in[18];
    const float* bao   = (const float*)d_in[19];
    const float* Wg    = (const float*)d_in[20];
    const float* bg    = (const float*)d_in[21];
    const float* Wo    = (const float*)d_in[22];
    const float* bo    = (const float*)d_in[23];

    // workspace layout (floats), extent 4,456,448 f = 17.83 MB (R6/R7-proven):
    float* ws    = (float*)d_ws;
    float* agg   = ws;                       // [0, 262144)
    float* comb  = agg  + N_ATOMS * 64;      // [262144, 786432)
    float* h1    = comb + N_ATOMS * 128;     // [786432, 1310720)
    float* upd   = h1   + N_ATOMS * 128;     // [1310720, 1835008)
    float* qkvf  = upd  + N_ATOMS * 128;     // [1835008, 3407872)
    float* attd  = qkvf + N_ATOMS * 384;     // [3407872, 3932160)
    float* aob   = attd + N_ATOMS * 128;     // [3932160, 4456448)
    // time-disjoint aliases:
    float* Wsl   = aob;                      // 73728 f; used t4..t5; aob written t11
    float* outp  = comb;                     // comb last read by qkprep (t8)... see order
    // sort scratch inside attd region (dead until attn writes it):
    int* deg     = (int*)attd;               // 4096
    int* base    = deg + 4096;               // 4096
    int* cur     = base + 4096;              // 4096
    int* sortedE = cur + 4096;               // 131072  (total 143360 < 524288)
    // fp16 attention operand buffers (time-disjoint):
    h16* Qhb = (h16*)comb;                   // comb dead after gemm m1; overwritten by outp later
    h16* Khb = Qhb + 4 * 4096 * 32;          // second MB of comb region
    h16* VTb = (h16*)h1;                     // h1 dead after gemm m2

    hipMemsetAsync(deg, 0, 4096 * sizeof(int), stream);

    count_kernel<<<512, 256, 0, stream>>>(eidx, deg);
    scan_kernel<<<1, 1024, 0, stream>>>(deg, base, cur);
    scatter_kernel<<<512, 256, 0, stream>>>(eidx, cur, sortedE);

    wprep_kernel<<<288, 256, 0, stream>>>(Wtp, Wsl);

    agg_kernel<<<N_ATOMS, 128, 0, stream>>>(
        evec, elen, sortedE, base, deg, Wr1, br1, Wr2, br2, Wsl, btp, agg);

    combined_kernel<<<(N_ATOMS * 64) / 256, 256, 0, stream>>>(an, emb, agg, comb);

    gemm128<1><<<dim3(64, 2), 256, 0, stream>>>(comb, Wm1, bm1, h1, 128, nullptr, nullptr);
    gemm128<0><<<dim3(64, 2), 256, 0, stream>>>(h1, Wm2, bm2, upd, 128, nullptr, nullptr);
    gemm128<0><<<dim3(64, 6), 256, 0, stream>>>(upd, Wqkv, bqkv, qkvf, 384, nullptr, nullptr);

    qkprep_kernel<<<2048, 256, 0, stream>>>(qkvf, Qhb, Khb);
    vtprep_kernel<<<2048, 256, 0, stream>>>(qkvf, VTb);

    attn_kernel<<<1024, 256, 0, stream>>>(Qhb, Khb, VTb, attd);

    gemm128<0><<<dim3(64, 2), 256, 0, stream>>>(attd, Wao, bao, aob, 128, nullptr, nullptr);
    gemm128<2><<<dim3(64, 2), 256, 0, stream>>>(upd, Wg, bg, outp, 128, aob, upd);
    gemm128<0><<<dim3(64, 2), 256, 0, stream>>>(outp, Wo, bo, (float*)d_out, 128, nullptr, nullptr);
}